// Round 1
// baseline (886.325 us; speedup 1.0000x reference)
//
#include <hip/hip_runtime.h>
#include <hip/hip_bf16.h>

#define N_NODES 10000
#define N_EDGES 320000
#define H 128
#define H2 256
#define NLAYERS 4
#define NG 64
#define NC 10
#define MSG_EPS 1e-7f
#define LN_EPS 1e-5f

// ---------------- CSR build (edge permutation sorted by dst) ----------------

__global__ __launch_bounds__(256) void count_kernel(const int* __restrict__ dst,
                                                    int* __restrict__ counts) {
    int e = blockIdx.x * 256 + threadIdx.x;
    if (e < N_EDGES) atomicAdd(&counts[dst[e]], 1);
}

__global__ __launch_bounds__(256) void scan_kernel(const int* __restrict__ counts,
                                                   int* __restrict__ off,
                                                   int* __restrict__ cursor) {
    __shared__ int part[256];
    int tid = threadIdx.x;
    const int CH = (N_NODES + 255) / 256;  // 40
    int base = tid * CH;
    int s = 0;
    for (int i = 0; i < CH; ++i) {
        int idx = base + i;
        if (idx < N_NODES) s += counts[idx];
    }
    part[tid] = s;
    __syncthreads();
    for (int d = 1; d < 256; d <<= 1) {
        int t = (tid >= d) ? part[tid - d] : 0;
        __syncthreads();
        part[tid] += t;
        __syncthreads();
    }
    int run = part[tid] - s;  // exclusive prefix for this chunk
    for (int i = 0; i < CH; ++i) {
        int idx = base + i;
        if (idx < N_NODES) {
            off[idx] = run;
            cursor[idx] = run;
            run += counts[idx];
        }
    }
    if (tid == 255) off[N_NODES] = run;  // = N_EDGES
}

__global__ __launch_bounds__(256) void scatter_kernel(const int* __restrict__ dst,
                                                      int* __restrict__ cursor,
                                                      int* __restrict__ perm) {
    int e = blockIdx.x * 256 + threadIdx.x;
    if (e < N_EDGES) {
        int p = atomicAdd(&cursor[dst[e]], 1);
        perm[p] = e;
    }
}

// ---------------- encoder: h = x @ enc_W + enc_b ----------------

__global__ __launch_bounds__(128) void encoder_kernel(const float* __restrict__ x,
                                                      const float* __restrict__ W,
                                                      const float* __restrict__ b,
                                                      float* __restrict__ h) {
    __shared__ float sx[8][H];
    int v0 = blockIdx.x * 8;
    int tid = threadIdx.x;
    for (int idx = tid; idx < 8 * H; idx += 128)
        sx[idx >> 7][idx & 127] = x[v0 * H + idx];
    __syncthreads();
    float y[8] = {0.f, 0.f, 0.f, 0.f, 0.f, 0.f, 0.f, 0.f};
    for (int k = 0; k < H; ++k) {
        float w = W[k * H + tid];
#pragma unroll
        for (int n = 0; n < 8; ++n) y[n] += sx[n][k] * w;
    }
    float bb = b[tid];
#pragma unroll
    for (int n = 0; n < 8; ++n) h[(v0 + n) * H + tid] = y[n] + bb;
}

// ---------------- pre-conv LN+ReLU (and final LN+ReLU+pool) ----------------

__global__ __launch_bounds__(128) void ln_relu_kernel(const float* __restrict__ h,
                                                      const float* __restrict__ g,
                                                      const float* __restrict__ b,
                                                      float* __restrict__ out,
                                                      const int* __restrict__ batch,
                                                      float* __restrict__ pooled,
                                                      int do_pool) {
    int v = blockIdx.x, tid = threadIdx.x;
    float x = h[v * H + tid];
    float s = x, sq = x * x;
    for (int d = 32; d; d >>= 1) {
        s += __shfl_down(s, d);
        sq += __shfl_down(sq, d);
    }
    __shared__ float ps[2][2];
    int w_ = tid >> 6, lane = tid & 63;
    if (lane == 0) { ps[w_][0] = s; ps[w_][1] = sq; }
    __syncthreads();
    float S = ps[0][0] + ps[1][0], SQ = ps[0][1] + ps[1][1];
    float mu = S * (1.f / H);
    float var = SQ * (1.f / H) - mu * mu;
    float rstd = rsqrtf(var + LN_EPS);
    float f = fmaxf((x - mu) * rstd * g[tid] + b[tid], 0.f);
    if (do_pool)
        atomicAdd(&pooled[batch[v] * H + tid], f);
    else
        out[v * H + tid] = f;
}

// ---------------- GENConv softmax aggregation (atomic-free, per-node) ----------------
// alpha = exp(m*t)/sum exp(m*t)  (max-subtraction skipped: identical ratio, m*t is small)
// u = sum(m*alpha) + x_v   (root skip)

__global__ __launch_bounds__(128) void edge_agg_kernel(const float* __restrict__ xcur,
                                                       const float* __restrict__ ea,
                                                       const int* __restrict__ src,
                                                       const int* __restrict__ off,
                                                       const int* __restrict__ perm,
                                                       const float* __restrict__ t, int l,
                                                       float* __restrict__ u) {
    int v = blockIdx.x, j = threadIdx.x;
    float tl = t[l];
    int b = off[v], e_end = off[v + 1];
    float xv = xcur[v * H + j];
    float den = 0.f, num = 0.f;
    // 1-deep software pipeline on the (uniform) index chain perm[i] -> src[e]
    int e_next = 0, s_next = 0;
    if (b < e_end) { e_next = perm[b]; s_next = src[e_next]; }
    for (int i = b; i < e_end; ++i) {
        int e = e_next, sidx = s_next;
        if (i + 1 < e_end) { e_next = perm[i + 1]; s_next = src[e_next]; }
        float m = fmaxf(xcur[sidx * H + j] + ea[(long)e * H + j], 0.f) + MSG_EPS;
        float ex = __expf(m * tl);
        den += ex;
        num += m * ex;
    }
    float agg = den > 0.f ? num / den : 0.f;
    u[v * H + j] = agg + xv;
}

// ---------------- GENConv MLP: Lin(H,2H) -> LN -> ReLU -> Lin(2H,H) (+res) ----------------

__global__ __launch_bounds__(256) void mlp_kernel(const float* __restrict__ u,
                                                  const float* __restrict__ hin,
                                                  float* __restrict__ hout,
                                                  const float* __restrict__ W1,
                                                  const float* __restrict__ b1,
                                                  const float* __restrict__ g1,
                                                  const float* __restrict__ be1,
                                                  const float* __restrict__ W2,
                                                  const float* __restrict__ b2,
                                                  int residual) {
    __shared__ float su[8][H];
    __shared__ float sa[8][H2];
    __shared__ float red[8][2];
    __shared__ float spart[8][H];
    int v0 = blockIdx.x * 8;
    int tid = threadIdx.x;
    for (int idx = tid; idx < 8 * H; idx += 256)
        su[idx >> 7][idx & 127] = u[v0 * H + idx];
    __syncthreads();
    // GEMM1: y[n] = dot(u_n, W1[:, tid])
    float y[8] = {0.f, 0.f, 0.f, 0.f, 0.f, 0.f, 0.f, 0.f};
    for (int k = 0; k < H; ++k) {
        float w = W1[k * H2 + tid];
#pragma unroll
        for (int n = 0; n < 8; ++n) y[n] += su[n][k] * w;
    }
    float bb = b1[tid];
#pragma unroll
    for (int n = 0; n < 8; ++n) { y[n] += bb; sa[n][tid] = y[n]; }
    __syncthreads();
    // LayerNorm over 2H per node: 4 waves x 2 nodes each
    int w_ = tid >> 6, lane = tid & 63;
    for (int nn = 0; nn < 2; ++nn) {
        int n = w_ * 2 + nn;
        float s = 0.f, sq = 0.f;
        for (int kk = lane; kk < H2; kk += 64) {
            float vv = sa[n][kk];
            s += vv;
            sq += vv * vv;
        }
        for (int d = 32; d; d >>= 1) {
            s += __shfl_down(s, d);
            sq += __shfl_down(sq, d);
        }
        if (lane == 0) {
            float mu = s * (1.f / H2);
            float var = sq * (1.f / H2) - mu * mu;
            red[n][0] = mu;
            red[n][1] = rsqrtf(var + LN_EPS);
        }
    }
    __syncthreads();
    float gg = g1[tid], bbeta = be1[tid];
#pragma unroll
    for (int n = 0; n < 8; ++n) {
        float a = fmaxf((y[n] - red[n][0]) * red[n][1] * gg + bbeta, 0.f);
        sa[n][tid] = a;
    }
    __syncthreads();
    // GEMM2: split k across two thread halves
    int c = tid & (H - 1), kh = tid >> 7;
    float z[8] = {0.f, 0.f, 0.f, 0.f, 0.f, 0.f, 0.f, 0.f};
    for (int k = kh * H; k < kh * H + H; ++k) {
        float w2 = W2[k * H + c];
#pragma unroll
        for (int n = 0; n < 8; ++n) z[n] += sa[n][k] * w2;
    }
    if (kh == 1) {
#pragma unroll
        for (int n = 0; n < 8; ++n) spart[n][c] = z[n];
    }
    __syncthreads();
    if (kh == 0) {
        float bb2 = b2[c];
#pragma unroll
        for (int n = 0; n < 8; ++n) {
            float zz = z[n] + spart[n][c] + bb2;
            int gi = (v0 + n) * H + c;
            hout[gi] = residual ? hin[gi] + zz : zz;
        }
    }
}

// ---------------- readout: logits + pooled copy ----------------

__global__ __launch_bounds__(640) void logits_kernel(const float* __restrict__ pooled,
                                                     const float* __restrict__ W,
                                                     const float* __restrict__ b,
                                                     float* __restrict__ out) {
    int tid = threadIdx.x;
    if (tid < NG * NC) {
        int g = tid / NC, c = tid % NC;
        float acc = b[c];
        for (int k = 0; k < H; ++k) acc += pooled[g * H + k] * W[k * NC + c];
        out[g * NC + c] = acc;
    }
    for (int idx = tid; idx < NG * H; idx += 640) out[NG * NC + idx] = pooled[idx];
}

// ---------------- launch ----------------

extern "C" void kernel_launch(void* const* d_in, const int* in_sizes, int n_in,
                              void* d_out, int out_size, void* d_ws, size_t ws_size,
                              hipStream_t stream) {
    const float* x     = (const float*)d_in[0];
    const float* ea    = (const float*)d_in[1];
    const float* enc_W = (const float*)d_in[2];
    const float* enc_b = (const float*)d_in[3];
    const float* t     = (const float*)d_in[4];
    const float* W1    = (const float*)d_in[5];
    const float* b1    = (const float*)d_in[6];
    const float* g1    = (const float*)d_in[7];
    const float* be1   = (const float*)d_in[8];
    const float* W2    = (const float*)d_in[9];
    const float* b2    = (const float*)d_in[10];
    const float* lng   = (const float*)d_in[11];
    const float* lnb   = (const float*)d_in[12];
    const float* linW  = (const float*)d_in[13];
    const float* linb  = (const float*)d_in[14];
    const int*   ei    = (const int*)d_in[15];
    const int*   batch = (const int*)d_in[16];
    const int* src = ei;
    const int* dst = ei + N_EDGES;
    float* out = (float*)d_out;

    float* h      = (float*)d_ws;
    float* r      = h + (size_t)N_NODES * H;
    float* u      = r + (size_t)N_NODES * H;
    float* pooled = u + (size_t)N_NODES * H;
    int* counts = (int*)(pooled + NG * H);
    int* off    = counts + N_NODES;
    int* cursor = off + N_NODES + 16;
    int* perm   = cursor + N_NODES;

    hipMemsetAsync(counts, 0, N_NODES * sizeof(int), stream);
    hipMemsetAsync(pooled, 0, NG * H * sizeof(float), stream);

    count_kernel<<<(N_EDGES + 255) / 256, 256, 0, stream>>>(dst, counts);
    scan_kernel<<<1, 256, 0, stream>>>(counts, off, cursor);
    scatter_kernel<<<(N_EDGES + 255) / 256, 256, 0, stream>>>(dst, cursor, perm);

    encoder_kernel<<<N_NODES / 8, 128, 0, stream>>>(x, enc_W, enc_b, h);

    for (int l = 0; l < NLAYERS; ++l) {
        const float* xcur;
        if (l == 0) {
            xcur = h;
        } else {
            ln_relu_kernel<<<N_NODES, 128, 0, stream>>>(h, lng + l * H, lnb + l * H, r,
                                                        nullptr, nullptr, 0);
            xcur = r;
        }
        edge_agg_kernel<<<N_NODES, 128, 0, stream>>>(xcur, ea, src, off, perm, t, l, u);
        mlp_kernel<<<N_NODES / 8, 256, 0, stream>>>(u, h, h,
                                                    W1 + (size_t)l * H * H2, b1 + l * H2,
                                                    g1 + l * H2, be1 + l * H2,
                                                    W2 + (size_t)l * H2 * H, b2 + l * H,
                                                    l > 0);
    }

    ln_relu_kernel<<<N_NODES, 128, 0, stream>>>(h, lng, lnb, nullptr, batch, pooled, 1);
    logits_kernel<<<1, 640, 0, stream>>>(pooled, linW, linb, out);
}

// Round 2
// 821.903 us; speedup vs baseline: 1.0784x; 1.0784x over previous
//
#include <hip/hip_runtime.h>
#include <hip/hip_bf16.h>

#define N_NODES 10000
#define N_EDGES 320000
#define H 128
#define H2 256
#define NLAYERS 4
#define NG 64
#define NC 10
#define MSG_EPS 1e-7f
#define LN_EPS 1e-5f

// ---------------- CSR build (edge permutation sorted by dst) ----------------

__global__ __launch_bounds__(256) void count_kernel(const int* __restrict__ dst,
                                                    int* __restrict__ counts) {
    int e = blockIdx.x * 256 + threadIdx.x;
    if (e < N_EDGES) atomicAdd(&counts[dst[e]], 1);
}

__global__ __launch_bounds__(256) void scan_kernel(const int* __restrict__ counts,
                                                   int* __restrict__ off,
                                                   int* __restrict__ cursor) {
    __shared__ int part[256];
    int tid = threadIdx.x;
    const int CH = (N_NODES + 255) / 256;  // 40
    int base = tid * CH;
    int s = 0;
    for (int i = 0; i < CH; ++i) {
        int idx = base + i;
        if (idx < N_NODES) s += counts[idx];
    }
    part[tid] = s;
    __syncthreads();
    for (int d = 1; d < 256; d <<= 1) {
        int t = (tid >= d) ? part[tid - d] : 0;
        __syncthreads();
        part[tid] += t;
        __syncthreads();
    }
    int run = part[tid] - s;  // exclusive prefix for this chunk
    for (int i = 0; i < CH; ++i) {
        int idx = base + i;
        if (idx < N_NODES) {
            off[idx] = run;
            cursor[idx] = run;
            run += counts[idx];
        }
    }
    if (tid == 255) off[N_NODES] = run;  // = N_EDGES
}

__global__ __launch_bounds__(256) void scatter_kernel(const int* __restrict__ src,
                                                      const int* __restrict__ dst,
                                                      int* __restrict__ cursor,
                                                      int* __restrict__ perm_e,
                                                      int* __restrict__ perm_s) {
    int e = blockIdx.x * 256 + threadIdx.x;
    if (e < N_EDGES) {
        int p = atomicAdd(&cursor[dst[e]], 1);
        perm_e[p] = e;
        perm_s[p] = src[e];  // pre-resolve src: kills one level of the load chain
    }
}

// ---------------- encoder: h = x @ enc_W + enc_b ----------------

__global__ __launch_bounds__(128) void encoder_kernel(const float* __restrict__ x,
                                                      const float* __restrict__ W,
                                                      const float* __restrict__ b,
                                                      float* __restrict__ h) {
    __shared__ float sx[8][H];
    int v0 = blockIdx.x * 8;
    int tid = threadIdx.x;
    for (int idx = tid; idx < 8 * H; idx += 128)
        sx[idx >> 7][idx & 127] = x[v0 * H + idx];
    __syncthreads();
    float y[8] = {0.f, 0.f, 0.f, 0.f, 0.f, 0.f, 0.f, 0.f};
    for (int k = 0; k < H; ++k) {
        float w = W[k * H + tid];
#pragma unroll
        for (int n = 0; n < 8; ++n) y[n] += sx[n][k] * w;
    }
    float bb = b[tid];
#pragma unroll
    for (int n = 0; n < 8; ++n) h[(v0 + n) * H + tid] = y[n] + bb;
}

// ---------------- pre-conv LN+ReLU (and final LN+ReLU+pool) ----------------

__global__ __launch_bounds__(128) void ln_relu_kernel(const float* __restrict__ h,
                                                      const float* __restrict__ g,
                                                      const float* __restrict__ b,
                                                      float* __restrict__ out,
                                                      const int* __restrict__ batch,
                                                      float* __restrict__ pooled,
                                                      int do_pool) {
    int v = blockIdx.x, tid = threadIdx.x;
    float x = h[v * H + tid];
    float s = x, sq = x * x;
    for (int d = 32; d; d >>= 1) {
        s += __shfl_down(s, d);
        sq += __shfl_down(sq, d);
    }
    __shared__ float ps[2][2];
    int w_ = tid >> 6, lane = tid & 63;
    if (lane == 0) { ps[w_][0] = s; ps[w_][1] = sq; }
    __syncthreads();
    float S = ps[0][0] + ps[1][0], SQ = ps[0][1] + ps[1][1];
    float mu = S * (1.f / H);
    float var = SQ * (1.f / H) - mu * mu;
    float rstd = rsqrtf(var + LN_EPS);
    float f = fmaxf((x - mu) * rstd * g[tid] + b[tid], 0.f);
    if (do_pool)
        atomicAdd(&pooled[batch[v] * H + tid], f);
    else
        out[v * H + tid] = f;
}

// ---------------- GENConv softmax aggregation (atomic-free, per-node) ----------------
// alpha = exp(m*t)/sum exp(m*t)  (max-subtraction skipped: identical ratio, m*t small)
// u = sum(m*alpha) + x_v   (root skip)
// 256 threads = 8 groups x 32 lanes; lane holds 4 features (float4).
// Each group walks every-8th edge, unrolled x2 -> up to 32x16B row-loads in flight.

#define PROC(cc)                                           \
    {                                                      \
        float m = fmaxf(xv.cc + ev.cc, 0.f) + MSG_EPS;     \
        float exx = __expf(m * tl);                        \
        den.cc += exx;                                     \
        num.cc += m * exx;                                 \
    }

__global__ __launch_bounds__(256) void edge_agg_kernel(const float* __restrict__ xcur,
                                                       const float* __restrict__ ea,
                                                       const int* __restrict__ off,
                                                       const int* __restrict__ perm_e,
                                                       const int* __restrict__ perm_s,
                                                       const float* __restrict__ t, int l,
                                                       float* __restrict__ u) {
    int v = blockIdx.x;
    int tid = threadIdx.x;
    int g = tid >> 5;     // edge group 0..7
    int lane = tid & 31;  // feature chunk (4 floats)
    float tl = t[l];
    int b = off[v], e_end = off[v + 1];
    const float4* x4 = (const float4*)xcur;
    const float4* e4 = (const float4*)ea;
    float4 den = {0.f, 0.f, 0.f, 0.f}, num = {0.f, 0.f, 0.f, 0.f};

    int i = b + g;
    for (; i + 8 < e_end; i += 16) {
        int e0 = perm_e[i], s0 = perm_s[i];
        int e1 = perm_e[i + 8], s1 = perm_s[i + 8];
        float4 xv0 = x4[(size_t)s0 * 32 + lane];
        float4 ev0 = e4[(size_t)e0 * 32 + lane];
        float4 xv1 = x4[(size_t)s1 * 32 + lane];
        float4 ev1 = e4[(size_t)e1 * 32 + lane];
        { float4 xv = xv0, ev = ev0; PROC(x) PROC(y) PROC(z) PROC(w) }
        { float4 xv = xv1, ev = ev1; PROC(x) PROC(y) PROC(z) PROC(w) }
    }
    for (; i < e_end; i += 8) {
        int e0 = perm_e[i], s0 = perm_s[i];
        float4 xv = x4[(size_t)s0 * 32 + lane];
        float4 ev = e4[(size_t)e0 * 32 + lane];
        PROC(x) PROC(y) PROC(z) PROC(w)
    }

    __shared__ float4 sden[8][32];
    __shared__ float4 snum[8][32];
    sden[g][lane] = den;
    snum[g][lane] = num;
    __syncthreads();
#pragma unroll
    for (int step = 4; step >= 1; step >>= 1) {
        if (g < step) {
            float4 a = sden[g][lane], b2 = sden[g + step][lane];
            a.x += b2.x; a.y += b2.y; a.z += b2.z; a.w += b2.w;
            sden[g][lane] = a;
            float4 c = snum[g][lane], d2 = snum[g + step][lane];
            c.x += d2.x; c.y += d2.y; c.z += d2.z; c.w += d2.w;
            snum[g][lane] = c;
        }
        __syncthreads();
    }
    if (g == 0) {
        float4 dn = sden[0][lane], nm = snum[0][lane];
        float4 xv = x4[(size_t)v * 32 + lane];
        float4 o;
        o.x = (dn.x > 0.f ? nm.x / dn.x : 0.f) + xv.x;
        o.y = (dn.y > 0.f ? nm.y / dn.y : 0.f) + xv.y;
        o.z = (dn.z > 0.f ? nm.z / dn.z : 0.f) + xv.z;
        o.w = (dn.w > 0.f ? nm.w / dn.w : 0.f) + xv.w;
        ((float4*)u)[(size_t)v * 32 + lane] = o;
    }
}

// ---------------- GENConv MLP: Lin(H,2H) -> LN -> ReLU -> Lin(2H,H) (+res) ----------------

__global__ __launch_bounds__(256) void mlp_kernel(const float* __restrict__ u,
                                                  const float* __restrict__ hin,
                                                  float* __restrict__ hout,
                                                  const float* __restrict__ W1,
                                                  const float* __restrict__ b1,
                                                  const float* __restrict__ g1,
                                                  const float* __restrict__ be1,
                                                  const float* __restrict__ W2,
                                                  const float* __restrict__ b2,
                                                  int residual) {
    __shared__ float su[8][H];
    __shared__ float sa[8][H2];
    __shared__ float red[8][2];
    __shared__ float spart[8][H];
    int v0 = blockIdx.x * 8;
    int tid = threadIdx.x;
    for (int idx = tid; idx < 8 * H; idx += 256)
        su[idx >> 7][idx & 127] = u[v0 * H + idx];
    __syncthreads();
    // GEMM1: y[n] = dot(u_n, W1[:, tid])
    float y[8] = {0.f, 0.f, 0.f, 0.f, 0.f, 0.f, 0.f, 0.f};
    for (int k = 0; k < H; ++k) {
        float w = W1[k * H2 + tid];
#pragma unroll
        for (int n = 0; n < 8; ++n) y[n] += su[n][k] * w;
    }
    float bb = b1[tid];
#pragma unroll
    for (int n = 0; n < 8; ++n) { y[n] += bb; sa[n][tid] = y[n]; }
    __syncthreads();
    // LayerNorm over 2H per node: 4 waves x 2 nodes each
    int w_ = tid >> 6, lane = tid & 63;
    for (int nn = 0; nn < 2; ++nn) {
        int n = w_ * 2 + nn;
        float s = 0.f, sq = 0.f;
        for (int kk = lane; kk < H2; kk += 64) {
            float vv = sa[n][kk];
            s += vv;
            sq += vv * vv;
        }
        for (int d = 32; d; d >>= 1) {
            s += __shfl_down(s, d);
            sq += __shfl_down(sq, d);
        }
        if (lane == 0) {
            float mu = s * (1.f / H2);
            float var = sq * (1.f / H2) - mu * mu;
            red[n][0] = mu;
            red[n][1] = rsqrtf(var + LN_EPS);
        }
    }
    __syncthreads();
    float gg = g1[tid], bbeta = be1[tid];
#pragma unroll
    for (int n = 0; n < 8; ++n) {
        float a = fmaxf((y[n] - red[n][0]) * red[n][1] * gg + bbeta, 0.f);
        sa[n][tid] = a;
    }
    __syncthreads();
    // GEMM2: split k across two thread halves
    int c = tid & (H - 1), kh = tid >> 7;
    float z[8] = {0.f, 0.f, 0.f, 0.f, 0.f, 0.f, 0.f, 0.f};
    for (int k = kh * H; k < kh * H + H; ++k) {
        float w2 = W2[k * H + c];
#pragma unroll
        for (int n = 0; n < 8; ++n) z[n] += sa[n][k] * w2;
    }
    if (kh == 1) {
#pragma unroll
        for (int n = 0; n < 8; ++n) spart[n][c] = z[n];
    }
    __syncthreads();
    if (kh == 0) {
        float bb2 = b2[c];
#pragma unroll
        for (int n = 0; n < 8; ++n) {
            float zz = z[n] + spart[n][c] + bb2;
            int gi = (v0 + n) * H + c;
            hout[gi] = residual ? hin[gi] + zz : zz;
        }
    }
}

// ---------------- readout: logits + pooled copy ----------------

__global__ __launch_bounds__(640) void logits_kernel(const float* __restrict__ pooled,
                                                     const float* __restrict__ W,
                                                     const float* __restrict__ b,
                                                     float* __restrict__ out) {
    int tid = threadIdx.x;
    if (tid < NG * NC) {
        int g = tid / NC, c = tid % NC;
        float acc = b[c];
        for (int k = 0; k < H; ++k) acc += pooled[g * H + k] * W[k * NC + c];
        out[g * NC + c] = acc;
    }
    for (int idx = tid; idx < NG * H; idx += 640) out[NG * NC + idx] = pooled[idx];
}

// ---------------- launch ----------------

extern "C" void kernel_launch(void* const* d_in, const int* in_sizes, int n_in,
                              void* d_out, int out_size, void* d_ws, size_t ws_size,
                              hipStream_t stream) {
    const float* x     = (const float*)d_in[0];
    const float* ea    = (const float*)d_in[1];
    const float* enc_W = (const float*)d_in[2];
    const float* enc_b = (const float*)d_in[3];
    const float* t     = (const float*)d_in[4];
    const float* W1    = (const float*)d_in[5];
    const float* b1    = (const float*)d_in[6];
    const float* g1    = (const float*)d_in[7];
    const float* be1   = (const float*)d_in[8];
    const float* W2    = (const float*)d_in[9];
    const float* b2    = (const float*)d_in[10];
    const float* lng   = (const float*)d_in[11];
    const float* lnb   = (const float*)d_in[12];
    const float* linW  = (const float*)d_in[13];
    const float* linb  = (const float*)d_in[14];
    const int*   ei    = (const int*)d_in[15];
    const int*   batch = (const int*)d_in[16];
    const int* src = ei;
    const int* dst = ei + N_EDGES;
    float* out = (float*)d_out;

    float* h      = (float*)d_ws;
    float* r      = h + (size_t)N_NODES * H;
    float* u      = r + (size_t)N_NODES * H;
    float* pooled = u + (size_t)N_NODES * H;
    int* counts = (int*)(pooled + NG * H);
    int* off    = counts + N_NODES;
    int* cursor = off + N_NODES + 16;
    int* perm_e = cursor + N_NODES;
    int* perm_s = perm_e + N_EDGES;

    hipMemsetAsync(counts, 0, N_NODES * sizeof(int), stream);
    hipMemsetAsync(pooled, 0, NG * H * sizeof(float), stream);

    count_kernel<<<(N_EDGES + 255) / 256, 256, 0, stream>>>(dst, counts);
    scan_kernel<<<1, 256, 0, stream>>>(counts, off, cursor);
    scatter_kernel<<<(N_EDGES + 255) / 256, 256, 0, stream>>>(src, dst, cursor, perm_e, perm_s);

    encoder_kernel<<<N_NODES / 8, 128, 0, stream>>>(x, enc_W, enc_b, h);

    for (int l = 0; l < NLAYERS; ++l) {
        const float* xcur;
        if (l == 0) {
            xcur = h;
        } else {
            ln_relu_kernel<<<N_NODES, 128, 0, stream>>>(h, lng + l * H, lnb + l * H, r,
                                                        nullptr, nullptr, 0);
            xcur = r;
        }
        edge_agg_kernel<<<N_NODES, 256, 0, stream>>>(xcur, ea, off, perm_e, perm_s, t, l, u);
        mlp_kernel<<<N_NODES / 8, 256, 0, stream>>>(u, h, h,
                                                    W1 + (size_t)l * H * H2, b1 + l * H2,
                                                    g1 + l * H2, be1 + l * H2,
                                                    W2 + (size_t)l * H2 * H, b2 + l * H,
                                                    l > 0);
    }

    ln_relu_kernel<<<N_NODES, 128, 0, stream>>>(h, lng, lnb, nullptr, batch, pooled, 1);
    logits_kernel<<<1, 640, 0, stream>>>(pooled, linW, linb, out);
}

// Round 3
// 614.905 us; speedup vs baseline: 1.4414x; 1.3366x over previous
//
#include <hip/hip_runtime.h>
#include <hip/hip_bf16.h>

#define N_NODES 10000
#define N_EDGES 320000
#define H 128
#define H2 256
#define NLAYERS 4
#define NG 64
#define NC 10
#define MSG_EPS 1e-7f
#define LN_EPS 1e-5f

typedef __attribute__((ext_vector_type(8))) short bf16x8;
typedef __attribute__((ext_vector_type(4))) float f32x4;

__device__ __forceinline__ short f2bf(float f) {
    union { float f; unsigned u; } x; x.f = f;
    unsigned r = x.u + 0x7FFFu + ((x.u >> 16) & 1u);  // RNE
    return (short)(r >> 16);
}

// ---------------- CSR build (edge permutation sorted by dst) ----------------

__global__ __launch_bounds__(256) void count_kernel(const int* __restrict__ dst,
                                                    int* __restrict__ counts) {
    int e = blockIdx.x * 256 + threadIdx.x;
    if (e < N_EDGES) atomicAdd(&counts[dst[e]], 1);
}

__global__ __launch_bounds__(256) void scan_kernel(const int* __restrict__ counts,
                                                   int* __restrict__ off,
                                                   int* __restrict__ cursor) {
    __shared__ int part[256];
    int tid = threadIdx.x;
    const int CH = (N_NODES + 255) / 256;  // 40
    int base = tid * CH;
    int s = 0;
    for (int i = 0; i < CH; ++i) {
        int idx = base + i;
        if (idx < N_NODES) s += counts[idx];
    }
    part[tid] = s;
    __syncthreads();
    for (int d = 1; d < 256; d <<= 1) {
        int t = (tid >= d) ? part[tid - d] : 0;
        __syncthreads();
        part[tid] += t;
        __syncthreads();
    }
    int run = part[tid] - s;
    for (int i = 0; i < CH; ++i) {
        int idx = base + i;
        if (idx < N_NODES) {
            off[idx] = run;
            cursor[idx] = run;
            run += counts[idx];
        }
    }
    if (tid == 255) off[N_NODES] = run;
}

__global__ __launch_bounds__(256) void scatter_kernel(const int* __restrict__ src,
                                                      const int* __restrict__ dst,
                                                      int* __restrict__ cursor,
                                                      int* __restrict__ perm_e,
                                                      int* __restrict__ perm_s) {
    int e = blockIdx.x * 256 + threadIdx.x;
    if (e < N_EDGES) {
        int p = atomicAdd(&cursor[dst[e]], 1);
        perm_e[p] = e;
        perm_s[p] = src[e];
    }
}

// ---------------- weight transpose + bf16 convert ----------------
// W1T[l][c][k] = bf16(W1[l][k][c])  (k-contiguous for MFMA B-frag loads)
// W2T[l][c][k] = bf16(W2[l][k][c])

__global__ __launch_bounds__(256) void wconv_kernel(const float* __restrict__ W1,
                                                    const float* __restrict__ W2,
                                                    short* __restrict__ W1T,
                                                    short* __restrict__ W2T) {
    int idx = blockIdx.x * 256 + threadIdx.x;
    if (idx < NLAYERS * H * H2) {
        int k = idx & (H - 1);
        int c = (idx >> 7) & (H2 - 1);
        int l = idx >> 15;
        W1T[idx] = f2bf(W1[l * H * H2 + k * H2 + c]);
        int k2 = idx & (H2 - 1);
        int c2 = (idx >> 8) & (H - 1);
        W2T[idx] = f2bf(W2[l * H * H2 + k2 * H + c2]);
    }
}

// ---------------- encoder: h = x @ enc_W + enc_b ----------------

__global__ __launch_bounds__(128) void encoder_kernel(const float* __restrict__ x,
                                                      const float* __restrict__ W,
                                                      const float* __restrict__ b,
                                                      float* __restrict__ h) {
    __shared__ float sx[8][H];
    int v0 = blockIdx.x * 8;
    int tid = threadIdx.x;
    for (int idx = tid; idx < 8 * H; idx += 128)
        sx[idx >> 7][idx & 127] = x[v0 * H + idx];
    __syncthreads();
    float y[8] = {0.f, 0.f, 0.f, 0.f, 0.f, 0.f, 0.f, 0.f};
    for (int k = 0; k < H; ++k) {
        float w = W[k * H + tid];
#pragma unroll
        for (int n = 0; n < 8; ++n) y[n] += sx[n][k] * w;
    }
    float bb = b[tid];
#pragma unroll
    for (int n = 0; n < 8; ++n) h[(v0 + n) * H + tid] = y[n] + bb;
}

// ---------------- LN+ReLU, wave-per-node (and final pool variant) ----------------

__global__ __launch_bounds__(256) void ln_relu_kernel(const float* __restrict__ h,
                                                      const float* __restrict__ g,
                                                      const float* __restrict__ b,
                                                      float* __restrict__ out,
                                                      const int* __restrict__ batch,
                                                      float* __restrict__ pooled,
                                                      int do_pool) {
    int wave = threadIdx.x >> 6, lane = threadIdx.x & 63;
    int v = blockIdx.x * 4 + wave;
    if (v >= N_NODES) return;
    float2 x = ((const float2*)(h + (size_t)v * H))[lane];
    float s = x.x + x.y, sq = x.x * x.x + x.y * x.y;
    for (int d = 32; d; d >>= 1) {
        s += __shfl_down(s, d);
        sq += __shfl_down(sq, d);
    }
    s = __shfl(s, 0);
    sq = __shfl(sq, 0);
    float mu = s * (1.f / H);
    float var = sq * (1.f / H) - mu * mu;
    float rstd = rsqrtf(var + LN_EPS);
    float2 gg = ((const float2*)g)[lane];
    float2 bb = ((const float2*)b)[lane];
    float f0 = fmaxf((x.x - mu) * rstd * gg.x + bb.x, 0.f);
    float f1 = fmaxf((x.y - mu) * rstd * gg.y + bb.y, 0.f);
    if (do_pool) {
        float* p = pooled + (size_t)batch[v] * H + lane * 2;
        atomicAdd(p, f0);
        atomicAdd(p + 1, f1);
    } else {
        ((float2*)(out + (size_t)v * H))[lane] = make_float2(f0, f1);
    }
}

// ---------------- GENConv softmax aggregation (atomic-free, per-node) ----------------

#define PROC(cc)                                           \
    {                                                      \
        float m = fmaxf(xv.cc + ev.cc, 0.f) + MSG_EPS;     \
        float exx = __expf(m * tl);                        \
        den.cc += exx;                                     \
        num.cc += m * exx;                                 \
    }

__global__ __launch_bounds__(256) void edge_agg_kernel(const float* __restrict__ xcur,
                                                       const float* __restrict__ ea,
                                                       const int* __restrict__ off,
                                                       const int* __restrict__ perm_e,
                                                       const int* __restrict__ perm_s,
                                                       const float* __restrict__ t, int l,
                                                       float* __restrict__ u) {
    int v = blockIdx.x;
    int tid = threadIdx.x;
    int g = tid >> 5;
    int lane = tid & 31;
    float tl = t[l];
    int b = off[v], e_end = off[v + 1];
    const float4* x4 = (const float4*)xcur;
    const float4* e4 = (const float4*)ea;
    float4 den = {0.f, 0.f, 0.f, 0.f}, num = {0.f, 0.f, 0.f, 0.f};

    int i = b + g;
    for (; i + 24 < e_end; i += 32) {
        int e0 = perm_e[i],      s0 = perm_s[i];
        int e1 = perm_e[i + 8],  s1 = perm_s[i + 8];
        int e2 = perm_e[i + 16], s2 = perm_s[i + 16];
        int e3 = perm_e[i + 24], s3 = perm_s[i + 24];
        float4 xv0 = x4[(size_t)s0 * 32 + lane], ev0 = e4[(size_t)e0 * 32 + lane];
        float4 xv1 = x4[(size_t)s1 * 32 + lane], ev1 = e4[(size_t)e1 * 32 + lane];
        float4 xv2 = x4[(size_t)s2 * 32 + lane], ev2 = e4[(size_t)e2 * 32 + lane];
        float4 xv3 = x4[(size_t)s3 * 32 + lane], ev3 = e4[(size_t)e3 * 32 + lane];
        { float4 xv = xv0, ev = ev0; PROC(x) PROC(y) PROC(z) PROC(w) }
        { float4 xv = xv1, ev = ev1; PROC(x) PROC(y) PROC(z) PROC(w) }
        { float4 xv = xv2, ev = ev2; PROC(x) PROC(y) PROC(z) PROC(w) }
        { float4 xv = xv3, ev = ev3; PROC(x) PROC(y) PROC(z) PROC(w) }
    }
    for (; i < e_end; i += 8) {
        int e0 = perm_e[i], s0 = perm_s[i];
        float4 xv = x4[(size_t)s0 * 32 + lane];
        float4 ev = e4[(size_t)e0 * 32 + lane];
        PROC(x) PROC(y) PROC(z) PROC(w)
    }

    __shared__ float4 sden[8][32];
    __shared__ float4 snum[8][32];
    sden[g][lane] = den;
    snum[g][lane] = num;
    __syncthreads();
#pragma unroll
    for (int step = 4; step >= 1; step >>= 1) {
        if (g < step) {
            float4 a = sden[g][lane], b2 = sden[g + step][lane];
            a.x += b2.x; a.y += b2.y; a.z += b2.z; a.w += b2.w;
            sden[g][lane] = a;
            float4 c = snum[g][lane], d2 = snum[g + step][lane];
            c.x += d2.x; c.y += d2.y; c.z += d2.z; c.w += d2.w;
            snum[g][lane] = c;
        }
        __syncthreads();
    }
    if (g == 0) {
        float4 dn = sden[0][lane], nm = snum[0][lane];
        float4 xv = x4[(size_t)v * 32 + lane];
        float4 o;
        o.x = (dn.x > 0.f ? nm.x / dn.x : 0.f) + xv.x;
        o.y = (dn.y > 0.f ? nm.y / dn.y : 0.f) + xv.y;
        o.z = (dn.z > 0.f ? nm.z / dn.z : 0.f) + xv.z;
        o.w = (dn.w > 0.f ? nm.w / dn.w : 0.f) + xv.w;
        ((float4*)u)[(size_t)v * 32 + lane] = o;
    }
}

// ---------------- GENConv MLP via bf16 MFMA ----------------
// 32 nodes/block, 256 threads (4 waves).
// GEMM1 [32x128]@[128x256]: wave w -> cols [w*64, w*64+64)
// LN(2H) in-register (16-lane shfl_xor reduce) -> ReLU -> bf16 A tile in LDS
// GEMM2 [32x256]@[256x128]: wave w -> cols [w*32, w*32+32)
// MFMA layouts (m89-verified): A row=lane&15,k=(lane>>4)*8+j; B col=lane&15,
// same k; C col=lane&15,row=(lane>>4)*4+j. LDS tiles XOR-swizzled in 16B
// chunks (chunk ^= row&7) -> <=2-way bank aliasing (free).

__global__ __launch_bounds__(256) void mlp_mfma_kernel(const float* __restrict__ u,
                                                       const float* __restrict__ hin,
                                                       float* __restrict__ hout,
                                                       const short* __restrict__ W1T,
                                                       const float* __restrict__ b1,
                                                       const float* __restrict__ g1,
                                                       const float* __restrict__ be1,
                                                       const short* __restrict__ W2T,
                                                       const float* __restrict__ b2,
                                                       int residual) {
    __shared__ short Ub[32 * 128];   // 8 KB
    __shared__ short Ab[32 * 256];   // 16 KB
    __shared__ float redv[2][32][4];
    __shared__ float musig[2][32];
    int tid = threadIdx.x;
    int wave = tid >> 6, lane = tid & 63;
    int l15 = lane & 15, lg = lane >> 4;
    int v0 = blockIdx.x * 32;
    int nrow = N_NODES - v0; if (nrow > 32) nrow = 32;

    // ---- stage U tile: f32 -> bf16, swizzled 16B chunks ----
    for (int c = tid; c < 32 * 16; c += 256) {
        int row = c >> 4, ch = c & 15;
        bf16x8 val = {0, 0, 0, 0, 0, 0, 0, 0};
        if (row < nrow) {
            const float4* up = (const float4*)(u + (size_t)(v0 + row) * H + ch * 8);
            float4 f0 = up[0], f1 = up[1];
            val[0] = f2bf(f0.x); val[1] = f2bf(f0.y); val[2] = f2bf(f0.z); val[3] = f2bf(f0.w);
            val[4] = f2bf(f1.x); val[5] = f2bf(f1.y); val[6] = f2bf(f1.z); val[7] = f2bf(f1.w);
        }
        *(bf16x8*)&Ub[row * 128 + ((ch ^ (row & 7)) * 8)] = val;
    }
    __syncthreads();

    // ---- GEMM1 ----
    int nc0 = wave * 64;
    f32x4 acc[2][4];
#pragma unroll
    for (int mi = 0; mi < 2; ++mi)
#pragma unroll
        for (int ni = 0; ni < 4; ++ni) acc[mi][ni] = (f32x4){0.f, 0.f, 0.f, 0.f};
#pragma unroll
    for (int ks = 0; ks < 4; ++ks) {
        bf16x8 af[2], bfr[4];
#pragma unroll
        for (int mi = 0; mi < 2; ++mi) {
            int row = mi * 16 + l15;
            int ch = ks * 4 + lg;
            af[mi] = *(const bf16x8*)&Ub[row * 128 + ((ch ^ (row & 7)) * 8)];
        }
#pragma unroll
        for (int ni = 0; ni < 4; ++ni) {
            int col = nc0 + ni * 16 + l15;
            bfr[ni] = *(const bf16x8*)&W1T[col * H + ks * 32 + lg * 8];
        }
#pragma unroll
        for (int mi = 0; mi < 2; ++mi)
#pragma unroll
            for (int ni = 0; ni < 4; ++ni)
                acc[mi][ni] = __builtin_amdgcn_mfma_f32_16x16x32_bf16(af[mi], bfr[ni], acc[mi][ni], 0, 0, 0);
    }

    // ---- bias + per-row (sum, sumsq) over this wave's 64 cols ----
    float bcol[4];
#pragma unroll
    for (int ni = 0; ni < 4; ++ni) bcol[ni] = b1[nc0 + ni * 16 + l15];
#pragma unroll
    for (int mi = 0; mi < 2; ++mi) {
#pragma unroll
        for (int j = 0; j < 4; ++j) {
            float s = 0.f, q = 0.f;
#pragma unroll
            for (int ni = 0; ni < 4; ++ni) {
                float y = acc[mi][ni][j] + bcol[ni];
                acc[mi][ni][j] = y;
                s += y;
                q += y * y;
            }
#pragma unroll
            for (int m = 8; m >= 1; m >>= 1) {
                s += __shfl_xor(s, m);
                q += __shfl_xor(q, m);
            }
            if (l15 == 0) {
                int row = mi * 16 + lg * 4 + j;
                redv[0][row][wave] = s;
                redv[1][row][wave] = q;
            }
        }
    }
    __syncthreads();
    if (tid < 32) {
        float S = redv[0][tid][0] + redv[0][tid][1] + redv[0][tid][2] + redv[0][tid][3];
        float Q = redv[1][tid][0] + redv[1][tid][1] + redv[1][tid][2] + redv[1][tid][3];
        float mu = S * (1.f / H2);
        float var = Q * (1.f / H2) - mu * mu;
        musig[0][tid] = mu;
        musig[1][tid] = rsqrtf(var + LN_EPS);
    }
    __syncthreads();

    // ---- LN + ReLU -> Ab (bf16, swizzled) ----
    float gcol[4], becol[4];
#pragma unroll
    for (int ni = 0; ni < 4; ++ni) {
        gcol[ni] = g1[nc0 + ni * 16 + l15];
        becol[ni] = be1[nc0 + ni * 16 + l15];
    }
#pragma unroll
    for (int mi = 0; mi < 2; ++mi)
#pragma unroll
        for (int j = 0; j < 4; ++j) {
            int row = mi * 16 + lg * 4 + j;
            float mu = musig[0][row], rs = musig[1][row];
#pragma unroll
            for (int ni = 0; ni < 4; ++ni) {
                int col = nc0 + ni * 16 + l15;
                float a = fmaxf((acc[mi][ni][j] - mu) * rs * gcol[ni] + becol[ni], 0.f);
                int ch = col >> 3, o8 = col & 7;
                Ab[row * 256 + ((ch ^ (row & 7)) * 8) + o8] = f2bf(a);
            }
        }
    __syncthreads();

    // ---- GEMM2 ----
    int nc2 = wave * 32;
    f32x4 acc2[2][2];
#pragma unroll
    for (int mi = 0; mi < 2; ++mi)
#pragma unroll
        for (int ni = 0; ni < 2; ++ni) acc2[mi][ni] = (f32x4){0.f, 0.f, 0.f, 0.f};
#pragma unroll
    for (int ks = 0; ks < 8; ++ks) {
        bf16x8 af[2], bfr[2];
#pragma unroll
        for (int mi = 0; mi < 2; ++mi) {
            int row = mi * 16 + l15;
            int ch = ks * 4 + lg;
            af[mi] = *(const bf16x8*)&Ab[row * 256 + ((ch ^ (row & 7)) * 8)];
        }
#pragma unroll
        for (int ni = 0; ni < 2; ++ni) {
            int col = nc2 + ni * 16 + l15;
            bfr[ni] = *(const bf16x8*)&W2T[col * H2 + ks * 32 + lg * 8];
        }
#pragma unroll
        for (int mi = 0; mi < 2; ++mi)
#pragma unroll
            for (int ni = 0; ni < 2; ++ni)
                acc2[mi][ni] = __builtin_amdgcn_mfma_f32_16x16x32_bf16(af[mi], bfr[ni], acc2[mi][ni], 0, 0, 0);
    }

    // ---- epilogue: + b2 (+ residual) -> hout ----
#pragma unroll
    for (int ni = 0; ni < 2; ++ni) {
        int col = nc2 + ni * 16 + l15;
        float bb = b2[col];
#pragma unroll
        for (int mi = 0; mi < 2; ++mi)
#pragma unroll
            for (int j = 0; j < 4; ++j) {
                int row = mi * 16 + lg * 4 + j;
                if (row < nrow) {
                    size_t gi = (size_t)(v0 + row) * H + col;
                    float z = acc2[mi][ni][j] + bb;
                    hout[gi] = residual ? hin[gi] + z : z;
                }
            }
    }
}

// ---------------- readout: logits + pooled copy ----------------

__global__ __launch_bounds__(640) void logits_kernel(const float* __restrict__ pooled,
                                                     const float* __restrict__ W,
                                                     const float* __restrict__ b,
                                                     float* __restrict__ out) {
    int tid = threadIdx.x;
    if (tid < NG * NC) {
        int g = tid / NC, c = tid % NC;
        float acc = b[c];
        for (int k = 0; k < H; ++k) acc += pooled[g * H + k] * W[k * NC + c];
        out[g * NC + c] = acc;
    }
    for (int idx = tid; idx < NG * H; idx += 640) out[NG * NC + idx] = pooled[idx];
}

// ---------------- launch ----------------

extern "C" void kernel_launch(void* const* d_in, const int* in_sizes, int n_in,
                              void* d_out, int out_size, void* d_ws, size_t ws_size,
                              hipStream_t stream) {
    const float* x     = (const float*)d_in[0];
    const float* ea    = (const float*)d_in[1];
    const float* enc_W = (const float*)d_in[2];
    const float* enc_b = (const float*)d_in[3];
    const float* t     = (const float*)d_in[4];
    const float* W1    = (const float*)d_in[5];
    const float* b1    = (const float*)d_in[6];
    const float* g1    = (const float*)d_in[7];
    const float* be1   = (const float*)d_in[8];
    const float* W2    = (const float*)d_in[9];
    const float* b2    = (const float*)d_in[10];
    const float* lng   = (const float*)d_in[11];
    const float* lnb   = (const float*)d_in[12];
    const float* linW  = (const float*)d_in[13];
    const float* linb  = (const float*)d_in[14];
    const int*   ei    = (const int*)d_in[15];
    const int*   batch = (const int*)d_in[16];
    const int* src = ei;
    const int* dst = ei + N_EDGES;
    float* out = (float*)d_out;

    short* W1T = (short*)d_ws;                      // 4*256*128
    short* W2T = W1T + NLAYERS * H * H2;            // 4*128*256
    float* h      = (float*)(W2T + NLAYERS * H * H2);
    float* r      = h + (size_t)N_NODES * H;
    float* u      = r + (size_t)N_NODES * H;
    float* pooled = u + (size_t)N_NODES * H;
    int* counts = (int*)(pooled + NG * H);
    int* off    = counts + N_NODES;
    int* cursor = off + N_NODES + 16;
    int* perm_e = cursor + N_NODES;
    int* perm_s = perm_e + N_EDGES;

    hipMemsetAsync(counts, 0, N_NODES * sizeof(int), stream);
    hipMemsetAsync(pooled, 0, NG * H * sizeof(float), stream);

    count_kernel<<<(N_EDGES + 255) / 256, 256, 0, stream>>>(dst, counts);
    scan_kernel<<<1, 256, 0, stream>>>(counts, off, cursor);
    scatter_kernel<<<(N_EDGES + 255) / 256, 256, 0, stream>>>(src, dst, cursor, perm_e, perm_s);
    wconv_kernel<<<(NLAYERS * H * H2 + 255) / 256, 256, 0, stream>>>(W1, W2, W1T, W2T);

    encoder_kernel<<<N_NODES / 8, 128, 0, stream>>>(x, enc_W, enc_b, h);

    for (int l = 0; l < NLAYERS; ++l) {
        const float* xcur;
        if (l == 0) {
            xcur = h;
        } else {
            ln_relu_kernel<<<(N_NODES + 3) / 4, 256, 0, stream>>>(h, lng + l * H, lnb + l * H, r,
                                                                  nullptr, nullptr, 0);
            xcur = r;
        }
        edge_agg_kernel<<<N_NODES, 256, 0, stream>>>(xcur, ea, off, perm_e, perm_s, t, l, u);
        mlp_mfma_kernel<<<(N_NODES + 31) / 32, 256, 0, stream>>>(
            u, h, h, W1T + (size_t)l * H * H2, b1 + l * H2, g1 + l * H2, be1 + l * H2,
            W2T + (size_t)l * H * H2, b2 + l * H, l > 0);
    }

    ln_relu_kernel<<<(N_NODES + 3) / 4, 256, 0, stream>>>(h, lng, lnb, nullptr, batch, pooled, 1);
    logits_kernel<<<1, 640, 0, stream>>>(pooled, linW, linb, out);
}

// Round 4
// 612.513 us; speedup vs baseline: 1.4470x; 1.0039x over previous
//
#include <hip/hip_runtime.h>
#include <hip/hip_bf16.h>

#define N_NODES 10000
#define N_EDGES 320000
#define H 128
#define H2 256
#define NLAYERS 4
#define NG 64
#define NC 10
#define MSG_EPS 1e-7f
#define LN_EPS 1e-5f

typedef __attribute__((ext_vector_type(8))) short bf16x8;
typedef __attribute__((ext_vector_type(4))) float f32x4;

__device__ __forceinline__ short f2bf(float f) {
    union { float f; unsigned u; } x; x.f = f;
    unsigned r = x.u + 0x7FFFu + ((x.u >> 16) & 1u);  // RNE
    return (short)(r >> 16);
}
__device__ __forceinline__ unsigned short f2bfu(float f) {
    union { float f; unsigned u; } x; x.f = f;
    unsigned r = x.u + 0x7FFFu + ((x.u >> 16) & 1u);
    return (unsigned short)(r >> 16);
}
__device__ __forceinline__ float bf2f(unsigned short u) {
    union { unsigned u; float f; } x; x.u = ((unsigned)u) << 16;
    return x.f;
}

// ---------------- CSR build (edge permutation sorted by dst) ----------------

__global__ __launch_bounds__(256) void count_kernel(const int* __restrict__ dst,
                                                    int* __restrict__ counts) {
    int e = blockIdx.x * 256 + threadIdx.x;
    if (e < N_EDGES) atomicAdd(&counts[dst[e]], 1);
}

__global__ __launch_bounds__(256) void scan_kernel(const int* __restrict__ counts,
                                                   int* __restrict__ off,
                                                   int* __restrict__ cursor) {
    __shared__ int part[256];
    int tid = threadIdx.x;
    const int CH = (N_NODES + 255) / 256;  // 40
    int base = tid * CH;
    int s = 0;
    for (int i = 0; i < CH; ++i) {
        int idx = base + i;
        if (idx < N_NODES) s += counts[idx];
    }
    part[tid] = s;
    __syncthreads();
    for (int d = 1; d < 256; d <<= 1) {
        int t = (tid >= d) ? part[tid - d] : 0;
        __syncthreads();
        part[tid] += t;
        __syncthreads();
    }
    int run = part[tid] - s;
    for (int i = 0; i < CH; ++i) {
        int idx = base + i;
        if (idx < N_NODES) {
            off[idx] = run;
            cursor[idx] = run;
            run += counts[idx];
        }
    }
    if (tid == 255) off[N_NODES] = run;
}

__global__ __launch_bounds__(256) void scatter_kernel(const int* __restrict__ src,
                                                      const int* __restrict__ dst,
                                                      int* __restrict__ cursor,
                                                      int* __restrict__ perm_e,
                                                      int* __restrict__ perm_s) {
    int e = blockIdx.x * 256 + threadIdx.x;
    if (e < N_EDGES) {
        int p = atomicAdd(&cursor[dst[e]], 1);
        perm_e[p] = e;
        perm_s[p] = src[e];
    }
}

// ---------------- edge_attr permute to dst-sorted order + bf16 ----------------
// eap[i][:] = bf16(ea[perm_e[i]][:]) — after this, every layer streams ea
// SEQUENTIALLY instead of gathering 512B rows at random.

__global__ __launch_bounds__(256) void permute_ea_kernel(const float* __restrict__ ea,
                                                         const int* __restrict__ perm_e,
                                                         ushort* __restrict__ eap) {
    int g = threadIdx.x >> 5, lane = threadIdx.x & 31;
    int i = blockIdx.x * 8 + g;
    if (i < N_EDGES) {
        int e = perm_e[i];
        float4 v = ((const float4*)ea)[(size_t)e * 32 + lane];
        ushort4 o;
        o.x = f2bfu(v.x); o.y = f2bfu(v.y); o.z = f2bfu(v.z); o.w = f2bfu(v.w);
        ((ushort4*)eap)[(size_t)i * 32 + lane] = o;
    }
}

// ---------------- weight transpose + bf16 convert ----------------

__global__ __launch_bounds__(256) void wconv_kernel(const float* __restrict__ W1,
                                                    const float* __restrict__ W2,
                                                    short* __restrict__ W1T,
                                                    short* __restrict__ W2T) {
    int idx = blockIdx.x * 256 + threadIdx.x;
    if (idx < NLAYERS * H * H2) {
        int k = idx & (H - 1);
        int c = (idx >> 7) & (H2 - 1);
        int l = idx >> 15;
        W1T[idx] = f2bf(W1[l * H * H2 + k * H2 + c]);
        int k2 = idx & (H2 - 1);
        int c2 = (idx >> 8) & (H - 1);
        W2T[idx] = f2bf(W2[l * H * H2 + k2 * H + c2]);
    }
}

// ---------------- encoder: h = x @ enc_W + enc_b ----------------

__global__ __launch_bounds__(128) void encoder_kernel(const float* __restrict__ x,
                                                      const float* __restrict__ W,
                                                      const float* __restrict__ b,
                                                      float* __restrict__ h) {
    __shared__ float sx[8][H];
    int v0 = blockIdx.x * 8;
    int tid = threadIdx.x;
    for (int idx = tid; idx < 8 * H; idx += 128)
        sx[idx >> 7][idx & 127] = x[v0 * H + idx];
    __syncthreads();
    float y[8] = {0.f, 0.f, 0.f, 0.f, 0.f, 0.f, 0.f, 0.f};
    for (int k = 0; k < H; ++k) {
        float w = W[k * H + tid];
#pragma unroll
        for (int n = 0; n < 8; ++n) y[n] += sx[n][k] * w;
    }
    float bb = b[tid];
#pragma unroll
    for (int n = 0; n < 8; ++n) h[(v0 + n) * H + tid] = y[n] + bb;
}

// ---------------- LN+ReLU, wave-per-node (and final pool variant) ----------------

__global__ __launch_bounds__(256) void ln_relu_kernel(const float* __restrict__ h,
                                                      const float* __restrict__ g,
                                                      const float* __restrict__ b,
                                                      float* __restrict__ out,
                                                      const int* __restrict__ batch,
                                                      float* __restrict__ pooled,
                                                      int do_pool) {
    int wave = threadIdx.x >> 6, lane = threadIdx.x & 63;
    int v = blockIdx.x * 4 + wave;
    if (v >= N_NODES) return;
    float2 x = ((const float2*)(h + (size_t)v * H))[lane];
    float s = x.x + x.y, sq = x.x * x.x + x.y * x.y;
    for (int d = 32; d; d >>= 1) {
        s += __shfl_down(s, d);
        sq += __shfl_down(sq, d);
    }
    s = __shfl(s, 0);
    sq = __shfl(sq, 0);
    float mu = s * (1.f / H);
    float var = sq * (1.f / H) - mu * mu;
    float rstd = rsqrtf(var + LN_EPS);
    float2 gg = ((const float2*)g)[lane];
    float2 bb = ((const float2*)b)[lane];
    float f0 = fmaxf((x.x - mu) * rstd * gg.x + bb.x, 0.f);
    float f1 = fmaxf((x.y - mu) * rstd * gg.y + bb.y, 0.f);
    if (do_pool) {
        float* p = pooled + (size_t)batch[v] * H + lane * 2;
        atomicAdd(p, f0);
        atomicAdd(p + 1, f1);
    } else {
        ((float2*)(out + (size_t)v * H))[lane] = make_float2(f0, f1);
    }
}

// ---------------- GENConv softmax aggregation ----------------
// ea now pre-permuted (dst-sorted, bf16): sequential stream per node block.
// Only x[src] gathers remain random (x is L2/L3-resident, 5 MB).

#define PROC(cc)                                           \
    {                                                      \
        float m = fmaxf(xv.cc + ev.cc, 0.f) + MSG_EPS;     \
        float exx = __expf(m * tl);                        \
        den.cc += exx;                                     \
        num.cc += m * exx;                                 \
    }

__device__ __forceinline__ float4 bf4(ushort4 u) {
    return make_float4(bf2f(u.x), bf2f(u.y), bf2f(u.z), bf2f(u.w));
}

__global__ __launch_bounds__(256) void edge_agg_kernel(const float* __restrict__ xcur,
                                                       const ushort* __restrict__ eap,
                                                       const int* __restrict__ off,
                                                       const int* __restrict__ perm_s,
                                                       const float* __restrict__ t, int l,
                                                       float* __restrict__ u) {
    int v = blockIdx.x;
    int tid = threadIdx.x;
    int g = tid >> 5;
    int lane = tid & 31;
    float tl = t[l];
    int b = off[v], e_end = off[v + 1];
    const float4* x4 = (const float4*)xcur;
    const ushort4* e4 = (const ushort4*)eap;
    float4 den = {0.f, 0.f, 0.f, 0.f}, num = {0.f, 0.f, 0.f, 0.f};

    int i = b + g;
    for (; i + 24 < e_end; i += 32) {
        int s0 = perm_s[i], s1 = perm_s[i + 8], s2 = perm_s[i + 16], s3 = perm_s[i + 24];
        float4 xv0 = x4[(size_t)s0 * 32 + lane];
        ushort4 eb0 = e4[(size_t)i * 32 + lane];
        float4 xv1 = x4[(size_t)s1 * 32 + lane];
        ushort4 eb1 = e4[(size_t)(i + 8) * 32 + lane];
        float4 xv2 = x4[(size_t)s2 * 32 + lane];
        ushort4 eb2 = e4[(size_t)(i + 16) * 32 + lane];
        float4 xv3 = x4[(size_t)s3 * 32 + lane];
        ushort4 eb3 = e4[(size_t)(i + 24) * 32 + lane];
        { float4 xv = xv0, ev = bf4(eb0); PROC(x) PROC(y) PROC(z) PROC(w) }
        { float4 xv = xv1, ev = bf4(eb1); PROC(x) PROC(y) PROC(z) PROC(w) }
        { float4 xv = xv2, ev = bf4(eb2); PROC(x) PROC(y) PROC(z) PROC(w) }
        { float4 xv = xv3, ev = bf4(eb3); PROC(x) PROC(y) PROC(z) PROC(w) }
    }
    for (; i < e_end; i += 8) {
        int s0 = perm_s[i];
        float4 xv = x4[(size_t)s0 * 32 + lane];
        float4 ev = bf4(e4[(size_t)i * 32 + lane]);
        PROC(x) PROC(y) PROC(z) PROC(w)
    }

    __shared__ float4 sden[8][32];
    __shared__ float4 snum[8][32];
    sden[g][lane] = den;
    snum[g][lane] = num;
    __syncthreads();
#pragma unroll
    for (int step = 4; step >= 1; step >>= 1) {
        if (g < step) {
            float4 a = sden[g][lane], b2 = sden[g + step][lane];
            a.x += b2.x; a.y += b2.y; a.z += b2.z; a.w += b2.w;
            sden[g][lane] = a;
            float4 c = snum[g][lane], d2 = snum[g + step][lane];
            c.x += d2.x; c.y += d2.y; c.z += d2.z; c.w += d2.w;
            snum[g][lane] = c;
        }
        __syncthreads();
    }
    if (g == 0) {
        float4 dn = sden[0][lane], nm = snum[0][lane];
        float4 xv = x4[(size_t)v * 32 + lane];
        float4 o;
        o.x = (dn.x > 0.f ? nm.x / dn.x : 0.f) + xv.x;
        o.y = (dn.y > 0.f ? nm.y / dn.y : 0.f) + xv.y;
        o.z = (dn.z > 0.f ? nm.z / dn.z : 0.f) + xv.z;
        o.w = (dn.w > 0.f ? nm.w / dn.w : 0.f) + xv.w;
        ((float4*)u)[(size_t)v * 32 + lane] = o;
    }
}

// ---------------- GENConv MLP via bf16 MFMA ----------------
// 32 nodes/block, 256 threads (4 waves). Layouts m89-verified.

__global__ __launch_bounds__(256) void mlp_mfma_kernel(const float* __restrict__ u,
                                                       const float* __restrict__ hin,
                                                       float* __restrict__ hout,
                                                       const short* __restrict__ W1T,
                                                       const float* __restrict__ b1,
                                                       const float* __restrict__ g1,
                                                       const float* __restrict__ be1,
                                                       const short* __restrict__ W2T,
                                                       const float* __restrict__ b2,
                                                       int residual) {
    __shared__ short Ub[32 * 128];   // 8 KB
    __shared__ short Ab[32 * 256];   // 16 KB
    __shared__ float redv[2][32][4];
    __shared__ float musig[2][32];
    int tid = threadIdx.x;
    int wave = tid >> 6, lane = tid & 63;
    int l15 = lane & 15, lg = lane >> 4;
    int v0 = blockIdx.x * 32;
    int nrow = N_NODES - v0; if (nrow > 32) nrow = 32;

    for (int c = tid; c < 32 * 16; c += 256) {
        int row = c >> 4, ch = c & 15;
        bf16x8 val = {0, 0, 0, 0, 0, 0, 0, 0};
        if (row < nrow) {
            const float4* up = (const float4*)(u + (size_t)(v0 + row) * H + ch * 8);
            float4 f0 = up[0], f1 = up[1];
            val[0] = f2bf(f0.x); val[1] = f2bf(f0.y); val[2] = f2bf(f0.z); val[3] = f2bf(f0.w);
            val[4] = f2bf(f1.x); val[5] = f2bf(f1.y); val[6] = f2bf(f1.z); val[7] = f2bf(f1.w);
        }
        *(bf16x8*)&Ub[row * 128 + ((ch ^ (row & 7)) * 8)] = val;
    }
    __syncthreads();

    int nc0 = wave * 64;
    f32x4 acc[2][4];
#pragma unroll
    for (int mi = 0; mi < 2; ++mi)
#pragma unroll
        for (int ni = 0; ni < 4; ++ni) acc[mi][ni] = (f32x4){0.f, 0.f, 0.f, 0.f};
#pragma unroll
    for (int ks = 0; ks < 4; ++ks) {
        bf16x8 af[2], bfr[4];
#pragma unroll
        for (int mi = 0; mi < 2; ++mi) {
            int row = mi * 16 + l15;
            int ch = ks * 4 + lg;
            af[mi] = *(const bf16x8*)&Ub[row * 128 + ((ch ^ (row & 7)) * 8)];
        }
#pragma unroll
        for (int ni = 0; ni < 4; ++ni) {
            int col = nc0 + ni * 16 + l15;
            bfr[ni] = *(const bf16x8*)&W1T[col * H + ks * 32 + lg * 8];
        }
#pragma unroll
        for (int mi = 0; mi < 2; ++mi)
#pragma unroll
            for (int ni = 0; ni < 4; ++ni)
                acc[mi][ni] = __builtin_amdgcn_mfma_f32_16x16x32_bf16(af[mi], bfr[ni], acc[mi][ni], 0, 0, 0);
    }

    float bcol[4];
#pragma unroll
    for (int ni = 0; ni < 4; ++ni) bcol[ni] = b1[nc0 + ni * 16 + l15];
#pragma unroll
    for (int mi = 0; mi < 2; ++mi) {
#pragma unroll
        for (int j = 0; j < 4; ++j) {
            float s = 0.f, q = 0.f;
#pragma unroll
            for (int ni = 0; ni < 4; ++ni) {
                float y = acc[mi][ni][j] + bcol[ni];
                acc[mi][ni][j] = y;
                s += y;
                q += y * y;
            }
#pragma unroll
            for (int m = 8; m >= 1; m >>= 1) {
                s += __shfl_xor(s, m);
                q += __shfl_xor(q, m);
            }
            if (l15 == 0) {
                int row = mi * 16 + lg * 4 + j;
                redv[0][row][wave] = s;
                redv[1][row][wave] = q;
            }
        }
    }
    __syncthreads();
    if (tid < 32) {
        float S = redv[0][tid][0] + redv[0][tid][1] + redv[0][tid][2] + redv[0][tid][3];
        float Q = redv[1][tid][0] + redv[1][tid][1] + redv[1][tid][2] + redv[1][tid][3];
        float mu = S * (1.f / H2);
        float var = Q * (1.f / H2) - mu * mu;
        musig[0][tid] = mu;
        musig[1][tid] = rsqrtf(var + LN_EPS);
    }
    __syncthreads();

    float gcol[4], becol[4];
#pragma unroll
    for (int ni = 0; ni < 4; ++ni) {
        gcol[ni] = g1[nc0 + ni * 16 + l15];
        becol[ni] = be1[nc0 + ni * 16 + l15];
    }
#pragma unroll
    for (int mi = 0; mi < 2; ++mi)
#pragma unroll
        for (int j = 0; j < 4; ++j) {
            int row = mi * 16 + lg * 4 + j;
            float mu = musig[0][row], rs = musig[1][row];
#pragma unroll
            for (int ni = 0; ni < 4; ++ni) {
                int col = nc0 + ni * 16 + l15;
                float a = fmaxf((acc[mi][ni][j] - mu) * rs * gcol[ni] + becol[ni], 0.f);
                int ch = col >> 3, o8 = col & 7;
                Ab[row * 256 + ((ch ^ (row & 7)) * 8) + o8] = f2bf(a);
            }
        }
    __syncthreads();

    int nc2 = wave * 32;
    f32x4 acc2[2][2];
#pragma unroll
    for (int mi = 0; mi < 2; ++mi)
#pragma unroll
        for (int ni = 0; ni < 2; ++ni) acc2[mi][ni] = (f32x4){0.f, 0.f, 0.f, 0.f};
#pragma unroll
    for (int ks = 0; ks < 8; ++ks) {
        bf16x8 af[2], bfr[2];
#pragma unroll
        for (int mi = 0; mi < 2; ++mi) {
            int row = mi * 16 + l15;
            int ch = ks * 4 + lg;
            af[mi] = *(const bf16x8*)&Ab[row * 256 + ((ch ^ (row & 7)) * 8)];
        }
#pragma unroll
        for (int ni = 0; ni < 2; ++ni) {
            int col = nc2 + ni * 16 + l15;
            bfr[ni] = *(const bf16x8*)&W2T[col * H2 + ks * 32 + lg * 8];
        }
#pragma unroll
        for (int mi = 0; mi < 2; ++mi)
#pragma unroll
            for (int ni = 0; ni < 2; ++ni)
                acc2[mi][ni] = __builtin_amdgcn_mfma_f32_16x16x32_bf16(af[mi], bfr[ni], acc2[mi][ni], 0, 0, 0);
    }

#pragma unroll
    for (int ni = 0; ni < 2; ++ni) {
        int col = nc2 + ni * 16 + l15;
        float bb = b2[col];
#pragma unroll
        for (int mi = 0; mi < 2; ++mi)
#pragma unroll
            for (int j = 0; j < 4; ++j) {
                int row = mi * 16 + lg * 4 + j;
                if (row < nrow) {
                    size_t gi = (size_t)(v0 + row) * H + col;
                    float z = acc2[mi][ni][j] + bb;
                    hout[gi] = residual ? hin[gi] + z : z;
                }
            }
    }
}

// ---------------- readout: logits + pooled copy ----------------

__global__ __launch_bounds__(640) void logits_kernel(const float* __restrict__ pooled,
                                                     const float* __restrict__ W,
                                                     const float* __restrict__ b,
                                                     float* __restrict__ out) {
    int tid = threadIdx.x;
    if (tid < NG * NC) {
        int g = tid / NC, c = tid % NC;
        float acc = b[c];
        for (int k = 0; k < H; ++k) acc += pooled[g * H + k] * W[k * NC + c];
        out[g * NC + c] = acc;
    }
    for (int idx = tid; idx < NG * H; idx += 640) out[NG * NC + idx] = pooled[idx];
}

// ---------------- launch ----------------

extern "C" void kernel_launch(void* const* d_in, const int* in_sizes, int n_in,
                              void* d_out, int out_size, void* d_ws, size_t ws_size,
                              hipStream_t stream) {
    const float* x     = (const float*)d_in[0];
    const float* ea    = (const float*)d_in[1];
    const float* enc_W = (const float*)d_in[2];
    const float* enc_b = (const float*)d_in[3];
    const float* t     = (const float*)d_in[4];
    const float* W1    = (const float*)d_in[5];
    const float* b1    = (const float*)d_in[6];
    const float* g1    = (const float*)d_in[7];
    const float* be1   = (const float*)d_in[8];
    const float* W2    = (const float*)d_in[9];
    const float* b2    = (const float*)d_in[10];
    const float* lng   = (const float*)d_in[11];
    const float* lnb   = (const float*)d_in[12];
    const float* linW  = (const float*)d_in[13];
    const float* linb  = (const float*)d_in[14];
    const int*   ei    = (const int*)d_in[15];
    const int*   batch = (const int*)d_in[16];
    const int* src = ei;
    const int* dst = ei + N_EDGES;
    float* out = (float*)d_out;

    short* W1T   = (short*)d_ws;                       // 4*256*128 shorts
    short* W2T   = W1T + NLAYERS * H * H2;
    ushort* eap  = (ushort*)(W2T + NLAYERS * H * H2);  // E*H bf16 = 82 MB
    float* h     = (float*)(eap + (size_t)N_EDGES * H);
    float* r      = h + (size_t)N_NODES * H;
    float* u      = r + (size_t)N_NODES * H;
    float* pooled = u + (size_t)N_NODES * H;
    int* counts = (int*)(pooled + NG * H);
    int* off    = counts + N_NODES;
    int* cursor = off + N_NODES + 16;
    int* perm_e = cursor + N_NODES;
    int* perm_s = perm_e + N_EDGES;

    hipMemsetAsync(counts, 0, N_NODES * sizeof(int), stream);
    hipMemsetAsync(pooled, 0, NG * H * sizeof(float), stream);

    count_kernel<<<(N_EDGES + 255) / 256, 256, 0, stream>>>(dst, counts);
    scan_kernel<<<1, 256, 0, stream>>>(counts, off, cursor);
    scatter_kernel<<<(N_EDGES + 255) / 256, 256, 0, stream>>>(src, dst, cursor, perm_e, perm_s);
    permute_ea_kernel<<<N_EDGES / 8, 256, 0, stream>>>(ea, perm_e, eap);
    wconv_kernel<<<(NLAYERS * H * H2 + 255) / 256, 256, 0, stream>>>(W1, W2, W1T, W2T);

    encoder_kernel<<<N_NODES / 8, 128, 0, stream>>>(x, enc_W, enc_b, h);

    for (int l = 0; l < NLAYERS; ++l) {
        const float* xcur;
        if (l == 0) {
            xcur = h;
        } else {
            ln_relu_kernel<<<(N_NODES + 3) / 4, 256, 0, stream>>>(h, lng + l * H, lnb + l * H, r,
                                                                  nullptr, nullptr, 0);
            xcur = r;
        }
        edge_agg_kernel<<<N_NODES, 256, 0, stream>>>(xcur, eap, off, perm_s, t, l, u);
        mlp_mfma_kernel<<<(N_NODES + 31) / 32, 256, 0, stream>>>(
            u, h, h, W1T + (size_t)l * H * H2, b1 + l * H2, g1 + l * H2, be1 + l * H2,
            W2T + (size_t)l * H * H2, b2 + l * H, l > 0);
    }

    ln_relu_kernel<<<(N_NODES + 3) / 4, 256, 0, stream>>>(h, lng, lnb, nullptr, batch, pooled, 1);
    logits_kernel<<<1, 640, 0, stream>>>(pooled, linW, linb, out);
}

// Round 5
// 571.131 us; speedup vs baseline: 1.5519x; 1.0725x over previous
//
#include <hip/hip_runtime.h>
#include <hip/hip_bf16.h>

#define N_NODES 10000
#define N_EDGES 320000
#define H 128
#define H2 256
#define NLAYERS 4
#define NG 64
#define NC 10
#define MSG_EPS 1e-7f
#define LN_EPS 1e-5f

typedef __attribute__((ext_vector_type(8))) short bf16x8;
typedef __attribute__((ext_vector_type(4))) float f32x4;

__device__ __forceinline__ short f2bf(float f) {
    union { float f; unsigned u; } x; x.f = f;
    unsigned r = x.u + 0x7FFFu + ((x.u >> 16) & 1u);  // RNE
    return (short)(r >> 16);
}
__device__ __forceinline__ unsigned short f2bfu(float f) {
    union { float f; unsigned u; } x; x.f = f;
    unsigned r = x.u + 0x7FFFu + ((x.u >> 16) & 1u);
    return (unsigned short)(r >> 16);
}
__device__ __forceinline__ float bf2f(unsigned short u) {
    union { unsigned u; float f; } x; x.u = ((unsigned)u) << 16;
    return x.f;
}

// ---------------- CSR build ----------------

__global__ __launch_bounds__(256) void count_kernel(const int* __restrict__ dst,
                                                    int* __restrict__ counts) {
    int e = blockIdx.x * 256 + threadIdx.x;
    if (e < N_EDGES) atomicAdd(&counts[dst[e]], 1);
}

__global__ __launch_bounds__(256) void scan_kernel(const int* __restrict__ counts,
                                                   int* __restrict__ off,
                                                   int* __restrict__ cursor) {
    __shared__ int part[256];
    int tid = threadIdx.x;
    const int CH = (N_NODES + 255) / 256;  // 40
    int base = tid * CH;
    int s = 0;
    for (int i = 0; i < CH; ++i) {
        int idx = base + i;
        if (idx < N_NODES) s += counts[idx];
    }
    part[tid] = s;
    __syncthreads();
    for (int d = 1; d < 256; d <<= 1) {
        int t = (tid >= d) ? part[tid - d] : 0;
        __syncthreads();
        part[tid] += t;
        __syncthreads();
    }
    int run = part[tid] - s;
    for (int i = 0; i < CH; ++i) {
        int idx = base + i;
        if (idx < N_NODES) {
            off[idx] = run;
            cursor[idx] = run;
            run += counts[idx];
        }
    }
    if (tid == 255) off[N_NODES] = run;
}

// also emits inverse permutation invp[e] = sorted position, for scatter-style permute
__global__ __launch_bounds__(256) void scatter_kernel(const int* __restrict__ src,
                                                      const int* __restrict__ dst,
                                                      int* __restrict__ cursor,
                                                      int* __restrict__ perm_s,
                                                      int* __restrict__ invp) {
    int e = blockIdx.x * 256 + threadIdx.x;
    if (e < N_EDGES) {
        int p = atomicAdd(&cursor[dst[e]], 1);
        perm_s[p] = src[e];
        invp[e] = p;
    }
}

// ---------------- edge_attr permute: COALESCED read, scattered write (bf16) ----------------

__global__ __launch_bounds__(256) void permute_ea_kernel(const float* __restrict__ ea,
                                                         const int* __restrict__ invp,
                                                         ushort* __restrict__ eapb) {
    int g = threadIdx.x >> 5, lane = threadIdx.x & 31;
    int e = blockIdx.x * 8 + g;
    if (e < N_EDGES) {
        int p = invp[e];
        float4 v = ((const float4*)ea)[(size_t)e * 32 + lane];
        ushort4 o;
        o.x = f2bfu(v.x); o.y = f2bfu(v.y); o.z = f2bfu(v.z); o.w = f2bfu(v.w);
        ((ushort4*)eapb)[(size_t)p * 32 + lane] = o;   // random 256B write: fire-and-forget
    }
}

// ---------------- weight transpose + bf16 convert ----------------

__global__ __launch_bounds__(256) void wconv_kernel(const float* __restrict__ W1,
                                                    const float* __restrict__ W2,
                                                    short* __restrict__ W1T,
                                                    short* __restrict__ W2T) {
    int idx = blockIdx.x * 256 + threadIdx.x;
    if (idx < NLAYERS * H * H2) {
        int k = idx & (H - 1);
        int c = (idx >> 7) & (H2 - 1);
        int l = idx >> 15;
        W1T[idx] = f2bf(W1[l * H * H2 + k * H2 + c]);
        int k2 = idx & (H2 - 1);
        int c2 = (idx >> 8) & (H - 1);
        W2T[idx] = f2bf(W2[l * H * H2 + k2 * H + c2]);
    }
}

// ---------------- encoder: h = x @ enc_W + enc_b (f32 + bf16 copies) ----------------

__global__ __launch_bounds__(128) void encoder_kernel(const float* __restrict__ x,
                                                      const float* __restrict__ W,
                                                      const float* __restrict__ b,
                                                      float* __restrict__ h,
                                                      ushort* __restrict__ hb) {
    __shared__ float sx[8][H];
    int v0 = blockIdx.x * 8;
    int tid = threadIdx.x;
    for (int idx = tid; idx < 8 * H; idx += 128)
        sx[idx >> 7][idx & 127] = x[v0 * H + idx];
    __syncthreads();
    float y[8] = {0.f, 0.f, 0.f, 0.f, 0.f, 0.f, 0.f, 0.f};
    for (int k = 0; k < H; ++k) {
        float w = W[k * H + tid];
#pragma unroll
        for (int n = 0; n < 8; ++n) y[n] += sx[n][k] * w;
    }
    float bb = b[tid];
#pragma unroll
    for (int n = 0; n < 8; ++n) {
        float z = y[n] + bb;
        h[(v0 + n) * H + tid] = z;
        hb[(v0 + n) * H + tid] = f2bfu(z);
    }
}

// ---------------- GENConv softmax aggregation: wave-per-node, all-bf16 ----------------
// 64 lanes = 2 edge-halves x 32 feature-lanes (4 feats each). No LDS, no syncthreads.

#define PROCB(xu, eu, cc)                                        \
    {                                                            \
        float m = fmaxf(bf2f(xu.cc) + bf2f(eu.cc), 0.f) + MSG_EPS; \
        float exx = __expf(m * tl);                              \
        den.cc += exx;                                           \
        num.cc += m * exx;                                       \
    }
#define PROC4B(xu, eu) PROCB(xu, eu, x) PROCB(xu, eu, y) PROCB(xu, eu, z) PROCB(xu, eu, w)

__global__ __launch_bounds__(256) void edge_agg_kernel(const ushort* __restrict__ xb,
                                                       const ushort* __restrict__ eapb,
                                                       const int* __restrict__ off,
                                                       const int* __restrict__ perm_s,
                                                       const float* __restrict__ t, int l,
                                                       ushort* __restrict__ ub) {
    int tid = threadIdx.x;
    int v = blockIdx.x * 4 + (tid >> 6);
    int lane = tid & 63, half = lane >> 5, l32 = lane & 31;
    float tl = t[l];
    int b = off[v], e_end = off[v + 1];
    const ushort4* x4 = (const ushort4*)xb;
    const ushort4* e4 = (const ushort4*)eapb;
    float4 den = {0.f, 0.f, 0.f, 0.f}, num = {0.f, 0.f, 0.f, 0.f};

    int i = b + half;
    for (; i + 6 < e_end; i += 8) {
        int s0 = perm_s[i], s1 = perm_s[i + 2], s2 = perm_s[i + 4], s3 = perm_s[i + 6];
        ushort4 xv0 = x4[(size_t)s0 * 32 + l32], ev0 = e4[(size_t)i * 32 + l32];
        ushort4 xv1 = x4[(size_t)s1 * 32 + l32], ev1 = e4[(size_t)(i + 2) * 32 + l32];
        ushort4 xv2 = x4[(size_t)s2 * 32 + l32], ev2 = e4[(size_t)(i + 4) * 32 + l32];
        ushort4 xv3 = x4[(size_t)s3 * 32 + l32], ev3 = e4[(size_t)(i + 6) * 32 + l32];
        PROC4B(xv0, ev0)
        PROC4B(xv1, ev1)
        PROC4B(xv2, ev2)
        PROC4B(xv3, ev3)
    }
    for (; i < e_end; i += 2) {
        int s0 = perm_s[i];
        ushort4 xv = x4[(size_t)s0 * 32 + l32];
        ushort4 ev = e4[(size_t)i * 32 + l32];
        PROC4B(xv, ev)
    }

    // combine the two edge-halves (lane i <-> lane i+32 hold same features)
    den.x += __shfl_xor(den.x, 32); den.y += __shfl_xor(den.y, 32);
    den.z += __shfl_xor(den.z, 32); den.w += __shfl_xor(den.w, 32);
    num.x += __shfl_xor(num.x, 32); num.y += __shfl_xor(num.y, 32);
    num.z += __shfl_xor(num.z, 32); num.w += __shfl_xor(num.w, 32);

    if (half == 0) {
        ushort4 xvb = x4[(size_t)v * 32 + l32];
        ushort4 ob;
        ob.x = f2bfu((den.x > 0.f ? num.x / den.x : 0.f) + bf2f(xvb.x));
        ob.y = f2bfu((den.y > 0.f ? num.y / den.y : 0.f) + bf2f(xvb.y));
        ob.z = f2bfu((den.z > 0.f ? num.z / den.z : 0.f) + bf2f(xvb.z));
        ob.w = f2bfu((den.w > 0.f ? num.w / den.w : 0.f) + bf2f(xvb.w));
        ((ushort4*)ub)[(size_t)v * 32 + l32] = ob;
    }
}

// ---------------- GENConv MLP via bf16 MFMA, with FUSED next-layer LN+ReLU ----------------
// 32 nodes/block, 256 threads (4 waves). Layouts m89-verified.
// Epilogue: z = GEMM2 + b2 (+hin) -> h; then LN(gn,bn)+ReLU -> either bf16 xb
// for the next conv (final=0) or pooled atomics (final=1, uses lng[0]).

__global__ __launch_bounds__(256) void mlp_mfma_kernel(const ushort* __restrict__ ub,
                                                       const float* __restrict__ hin,
                                                       float* __restrict__ hout,
                                                       const short* __restrict__ W1T,
                                                       const float* __restrict__ b1,
                                                       const float* __restrict__ g1,
                                                       const float* __restrict__ be1,
                                                       const short* __restrict__ W2T,
                                                       const float* __restrict__ b2,
                                                       int residual,
                                                       const float* __restrict__ gn,
                                                       const float* __restrict__ bn,
                                                       ushort* __restrict__ rbout,
                                                       int final_pool,
                                                       const int* __restrict__ batch,
                                                       float* __restrict__ pooled) {
    __shared__ short Ub[32 * 128];   // 8 KB
    __shared__ short Ab[32 * 256];   // 16 KB
    __shared__ float redv[2][32][4];
    __shared__ float musig[2][32];
    int tid = threadIdx.x;
    int wave = tid >> 6, lane = tid & 63;
    int l15 = lane & 15, lg = lane >> 4;
    int v0 = blockIdx.x * 32;
    int nrow = N_NODES - v0; if (nrow > 32) nrow = 32;

    // ---- stage U tile (already bf16), swizzled 16B chunks ----
    for (int c = tid; c < 32 * 16; c += 256) {
        int row = c >> 4, ch = c & 15;
        bf16x8 val = {0, 0, 0, 0, 0, 0, 0, 0};
        if (row < nrow)
            val = *(const bf16x8*)&ub[(size_t)(v0 + row) * H + ch * 8];
        *(bf16x8*)&Ub[row * 128 + ((ch ^ (row & 7)) * 8)] = val;
    }
    __syncthreads();

    // ---- GEMM1 ----
    int nc0 = wave * 64;
    f32x4 acc[2][4];
#pragma unroll
    for (int mi = 0; mi < 2; ++mi)
#pragma unroll
        for (int ni = 0; ni < 4; ++ni) acc[mi][ni] = (f32x4){0.f, 0.f, 0.f, 0.f};
#pragma unroll
    for (int ks = 0; ks < 4; ++ks) {
        bf16x8 af[2], bfr[4];
#pragma unroll
        for (int mi = 0; mi < 2; ++mi) {
            int row = mi * 16 + l15;
            int ch = ks * 4 + lg;
            af[mi] = *(const bf16x8*)&Ub[row * 128 + ((ch ^ (row & 7)) * 8)];
        }
#pragma unroll
        for (int ni = 0; ni < 4; ++ni) {
            int col = nc0 + ni * 16 + l15;
            bfr[ni] = *(const bf16x8*)&W1T[col * H + ks * 32 + lg * 8];
        }
#pragma unroll
        for (int mi = 0; mi < 2; ++mi)
#pragma unroll
            for (int ni = 0; ni < 4; ++ni)
                acc[mi][ni] = __builtin_amdgcn_mfma_f32_16x16x32_bf16(af[mi], bfr[ni], acc[mi][ni], 0, 0, 0);
    }

    // ---- bias + per-row (sum, sumsq) ----
    float bcol[4];
#pragma unroll
    for (int ni = 0; ni < 4; ++ni) bcol[ni] = b1[nc0 + ni * 16 + l15];
#pragma unroll
    for (int mi = 0; mi < 2; ++mi) {
#pragma unroll
        for (int j = 0; j < 4; ++j) {
            float s = 0.f, q = 0.f;
#pragma unroll
            for (int ni = 0; ni < 4; ++ni) {
                float y = acc[mi][ni][j] + bcol[ni];
                acc[mi][ni][j] = y;
                s += y;
                q += y * y;
            }
#pragma unroll
            for (int m = 8; m >= 1; m >>= 1) {
                s += __shfl_xor(s, m);
                q += __shfl_xor(q, m);
            }
            if (l15 == 0) {
                int row = mi * 16 + lg * 4 + j;
                redv[0][row][wave] = s;
                redv[1][row][wave] = q;
            }
        }
    }
    __syncthreads();
    if (tid < 32) {
        float S = redv[0][tid][0] + redv[0][tid][1] + redv[0][tid][2] + redv[0][tid][3];
        float Q = redv[1][tid][0] + redv[1][tid][1] + redv[1][tid][2] + redv[1][tid][3];
        float mu = S * (1.f / H2);
        float var = Q * (1.f / H2) - mu * mu;
        musig[0][tid] = mu;
        musig[1][tid] = rsqrtf(var + LN_EPS);
    }
    __syncthreads();

    // ---- LN + ReLU -> Ab (bf16, swizzled) ----
    float gcol[4], becol[4];
#pragma unroll
    for (int ni = 0; ni < 4; ++ni) {
        gcol[ni] = g1[nc0 + ni * 16 + l15];
        becol[ni] = be1[nc0 + ni * 16 + l15];
    }
#pragma unroll
    for (int mi = 0; mi < 2; ++mi)
#pragma unroll
        for (int j = 0; j < 4; ++j) {
            int row = mi * 16 + lg * 4 + j;
            float mu = musig[0][row], rs = musig[1][row];
#pragma unroll
            for (int ni = 0; ni < 4; ++ni) {
                int col = nc0 + ni * 16 + l15;
                float a = fmaxf((acc[mi][ni][j] - mu) * rs * gcol[ni] + becol[ni], 0.f);
                int ch = col >> 3, o8 = col & 7;
                Ab[row * 256 + ((ch ^ (row & 7)) * 8) + o8] = f2bf(a);
            }
        }
    __syncthreads();

    // ---- GEMM2 ----
    int nc2 = wave * 32;
    f32x4 acc2[2][2];
#pragma unroll
    for (int mi = 0; mi < 2; ++mi)
#pragma unroll
        for (int ni = 0; ni < 2; ++ni) acc2[mi][ni] = (f32x4){0.f, 0.f, 0.f, 0.f};
#pragma unroll
    for (int ks = 0; ks < 8; ++ks) {
        bf16x8 af[2], bfr[2];
#pragma unroll
        for (int mi = 0; mi < 2; ++mi) {
            int row = mi * 16 + l15;
            int ch = ks * 4 + lg;
            af[mi] = *(const bf16x8*)&Ab[row * 256 + ((ch ^ (row & 7)) * 8)];
        }
#pragma unroll
        for (int ni = 0; ni < 2; ++ni) {
            int col = nc2 + ni * 16 + l15;
            bfr[ni] = *(const bf16x8*)&W2T[col * H2 + ks * 32 + lg * 8];
        }
#pragma unroll
        for (int mi = 0; mi < 2; ++mi)
#pragma unroll
            for (int ni = 0; ni < 2; ++ni)
                acc2[mi][ni] = __builtin_amdgcn_mfma_f32_16x16x32_bf16(af[mi], bfr[ni], acc2[mi][ni], 0, 0, 0);
    }

    // ---- epilogue: z = acc2 + b2 (+hin) -> h; fused LN(gn,bn)+ReLU ----
    float zz[2][2][4];
#pragma unroll
    for (int ni = 0; ni < 2; ++ni) {
        int col = nc2 + ni * 16 + l15;
        float bb = b2[col];
#pragma unroll
        for (int mi = 0; mi < 2; ++mi)
#pragma unroll
            for (int j = 0; j < 4; ++j) {
                int row = mi * 16 + lg * 4 + j;
                size_t gi = (size_t)(v0 + row) * H + col;
                float hv = (residual && row < nrow) ? hin[gi] : 0.f;
                float z = acc2[mi][ni][j] + bb + hv;
                zz[mi][ni][j] = z;
                if (row < nrow) hout[gi] = z;
            }
    }
    // per-row sums over this wave's 32 cols
#pragma unroll
    for (int mi = 0; mi < 2; ++mi)
#pragma unroll
        for (int j = 0; j < 4; ++j) {
            float s = zz[mi][0][j] + zz[mi][1][j];
            float q = zz[mi][0][j] * zz[mi][0][j] + zz[mi][1][j] * zz[mi][1][j];
#pragma unroll
            for (int m = 8; m >= 1; m >>= 1) {
                s += __shfl_xor(s, m);
                q += __shfl_xor(q, m);
            }
            if (l15 == 0) {
                int row = mi * 16 + lg * 4 + j;
                redv[0][row][wave] = s;
                redv[1][row][wave] = q;
            }
        }
    __syncthreads();
    if (tid < 32) {
        float S = redv[0][tid][0] + redv[0][tid][1] + redv[0][tid][2] + redv[0][tid][3];
        float Q = redv[1][tid][0] + redv[1][tid][1] + redv[1][tid][2] + redv[1][tid][3];
        float mu = S * (1.f / H);
        float var = Q * (1.f / H) - mu * mu;
        musig[0][tid] = mu;
        musig[1][tid] = rsqrtf(var + LN_EPS);
    }
    __syncthreads();
#pragma unroll
    for (int ni = 0; ni < 2; ++ni) {
        int col = nc2 + ni * 16 + l15;
        float gv = gn[col], bv = bn[col];
#pragma unroll
        for (int mi = 0; mi < 2; ++mi)
#pragma unroll
            for (int j = 0; j < 4; ++j) {
                int row = mi * 16 + lg * 4 + j;
                if (row < nrow) {
                    float rn = fmaxf((zz[mi][ni][j] - musig[0][row]) * musig[1][row] * gv + bv, 0.f);
                    if (final_pool)
                        atomicAdd(&pooled[(size_t)batch[v0 + row] * H + col], rn);
                    else
                        rbout[(size_t)(v0 + row) * H + col] = f2bfu(rn);
                }
            }
    }
}

// ---------------- readout: logits + pooled copy ----------------

__global__ __launch_bounds__(640) void logits_kernel(const float* __restrict__ pooled,
                                                     const float* __restrict__ W,
                                                     const float* __restrict__ b,
                                                     float* __restrict__ out) {
    int tid = threadIdx.x;
    if (tid < NG * NC) {
        int g = tid / NC, c = tid % NC;
        float acc = b[c];
        for (int k = 0; k < H; ++k) acc += pooled[g * H + k] * W[k * NC + c];
        out[g * NC + c] = acc;
    }
    for (int idx = tid; idx < NG * H; idx += 640) out[NG * NC + idx] = pooled[idx];
}

// ---------------- launch ----------------

extern "C" void kernel_launch(void* const* d_in, const int* in_sizes, int n_in,
                              void* d_out, int out_size, void* d_ws, size_t ws_size,
                              hipStream_t stream) {
    const float* x     = (const float*)d_in[0];
    const float* ea    = (const float*)d_in[1];
    const float* enc_W = (const float*)d_in[2];
    const float* enc_b = (const float*)d_in[3];
    const float* t     = (const float*)d_in[4];
    const float* W1    = (const float*)d_in[5];
    const float* b1    = (const float*)d_in[6];
    const float* g1    = (const float*)d_in[7];
    const float* be1   = (const float*)d_in[8];
    const float* W2    = (const float*)d_in[9];
    const float* b2    = (const float*)d_in[10];
    const float* lng   = (const float*)d_in[11];
    const float* lnb   = (const float*)d_in[12];
    const float* linW  = (const float*)d_in[13];
    const float* linb  = (const float*)d_in[14];
    const int*   ei    = (const int*)d_in[15];
    const int*   batch = (const int*)d_in[16];
    const int* src = ei;
    const int* dst = ei + N_EDGES;
    float* out = (float*)d_out;

    short*  W1T  = (short*)d_ws;                        // 4*256*128
    short*  W2T  = W1T + NLAYERS * H * H2;
    ushort* eapb = (ushort*)(W2T + NLAYERS * H * H2);   // E*H bf16
    ushort* xb   = eapb + (size_t)N_EDGES * H;          // N*H bf16 (xcur)
    ushort* ub   = xb + (size_t)N_NODES * H;            // N*H bf16 (conv out)
    float*  h    = (float*)(ub + (size_t)N_NODES * H);  // N*H f32
    float*  pooled = h + (size_t)N_NODES * H;
    int* counts = (int*)(pooled + NG * H);
    int* off    = counts + N_NODES;
    int* cursor = off + N_NODES + 16;
    int* perm_s = cursor + N_NODES;
    int* invp   = perm_s + N_EDGES;

    hipMemsetAsync(counts, 0, N_NODES * sizeof(int), stream);
    hipMemsetAsync(pooled, 0, NG * H * sizeof(float), stream);

    count_kernel<<<(N_EDGES + 255) / 256, 256, 0, stream>>>(dst, counts);
    scan_kernel<<<1, 256, 0, stream>>>(counts, off, cursor);
    scatter_kernel<<<(N_EDGES + 255) / 256, 256, 0, stream>>>(src, dst, cursor, perm_s, invp);
    permute_ea_kernel<<<N_EDGES / 8, 256, 0, stream>>>(ea, invp, eapb);
    wconv_kernel<<<(NLAYERS * H * H2 + 255) / 256, 256, 0, stream>>>(W1, W2, W1T, W2T);

    encoder_kernel<<<N_NODES / 8, 128, 0, stream>>>(x, enc_W, enc_b, h, xb);

    for (int l = 0; l < NLAYERS; ++l) {
        edge_agg_kernel<<<N_NODES / 4, 256, 0, stream>>>(xb, eapb, off, perm_s, t, l, ub);
        int final_pool = (l == NLAYERS - 1);
        const float* gn = final_pool ? lng : lng + (l + 1) * H;
        const float* bn = final_pool ? lnb : lnb + (l + 1) * H;
        mlp_mfma_kernel<<<(N_NODES + 31) / 32, 256, 0, stream>>>(
            ub, h, h, W1T + (size_t)l * H * H2, b1 + l * H2, g1 + l * H2, be1 + l * H2,
            W2T + (size_t)l * H * H2, b2 + l * H, l > 0,
            gn, bn, xb, final_pool, batch, pooled);
    }

    logits_kernel<<<1, 640, 0, stream>>>(pooled, linW, linb, out);
}